// Round 21
// baseline (172.817 us; speedup 1.0000x reference)
//
#include <hip/hip_runtime.h>
#include <hip/hip_bf16.h>
#include <stdint.h>

#define DIM  768
#define NHEAD 12
#define DK   64
#define BATCH 4
#define SEQ  2048
#define ROWS (BATCH*SEQ)   // 8192
#define SCL  0.1803368801111204f   /* (1/sqrt(64)) * log2(e) — folded into Q gemm epilogue */

typedef __bf16 bf16_t;
typedef bf16_t bf16x8 __attribute__((ext_vector_type(8)));
typedef bf16_t bf16x4 __attribute__((ext_vector_type(4)));
typedef float  f32x4  __attribute__((ext_vector_type(4)));
typedef float  f32x16 __attribute__((ext_vector_type(16)));

typedef unsigned int __attribute__((address_space(1)))* as1p;
typedef unsigned int __attribute__((address_space(3)))* as3p;

__device__ __forceinline__ void gload_lds16(const void* g, void* l) {
    __builtin_amdgcn_global_load_lds((as1p)g, (as3p)l, 16, 0, 0);
}
#define MEMFENCE asm volatile("" ::: "memory")
// NOTE: inline-asm v_permlane32_swap_b32 is BANNED (convicted R3/R4/R5/R7).

// ---------------- cast qkv fp32 -> bf16 ----------------
__global__ void cast_bf16_kernel(const float* __restrict__ in, bf16_t* __restrict__ out) {
    int i = blockIdx.x * 256 + threadIdx.x;
    const float4* p = (const float4*)in;
    float4 a = p[(size_t)i*2], b = p[(size_t)i*2+1];
    bf16x8 v;
    v[0]=(bf16_t)a.x; v[1]=(bf16_t)a.y; v[2]=(bf16_t)a.z; v[3]=(bf16_t)a.w;
    v[4]=(bf16_t)b.x; v[5]=(bf16_t)b.y; v[6]=(bf16_t)b.z; v[7]=(bf16_t)b.w;
    *(bf16x8*)(out + (size_t)i*8) = v;
}

// ---------------- transpose+cast weights: WT[j][i] = W[i][j] ----------------
__global__ void wtrans_kernel(const float* __restrict__ W0, const float* __restrict__ W1,
                              const float* __restrict__ W2, const float* __restrict__ W3,
                              bf16_t* __restrict__ T0, bf16_t* __restrict__ T1,
                              bf16_t* __restrict__ T2, bf16_t* __restrict__ T3) {
    const float* W = blockIdx.z==0?W0 : blockIdx.z==1?W1 : blockIdx.z==2?W2 : W3;
    bf16_t*      T = blockIdx.z==0?T0 : blockIdx.z==1?T1 : blockIdx.z==2?T2 : T3;
    __shared__ float tile[32][33];
    int tx = threadIdx.x, ty = threadIdx.y;          // 32 x 8
    int c = blockIdx.x*32 + tx;
    #pragma unroll
    for (int r = 0; r < 32; r += 8)
        tile[ty+r][tx] = W[(size_t)(blockIdx.y*32 + ty + r)*DIM + c];
    __syncthreads();
    int oc = blockIdx.y*32 + tx;
    #pragma unroll
    for (int r = 0; r < 32; r += 8)
        T[(size_t)(blockIdx.x*32 + ty + r)*DIM + oc] = (bf16_t)tile[tx][ty+r];
}

// ---------------- fused QKV GEMM: z folded into the K-loop ----------------
// Step-floor model (fit across R13/R14/R16/attn): every LDS+barrier loop pays
// ~3800-4200 cyc/step regardless of prefetch/conflicts/tile; only work-per-step
// moves perf. Fuse z: A-tile staged ONCE per block (3x less A traffic), 96 MFMA
// per wave per step (3x), block-steps 13824 -> 4608. LDS = As 16KB + Bs[3] 48KB
// single-buffered (2 blocks/CU); m97-style stage -> vmcnt(0) -> barrier -> compute
// (pipelining variants proven null R12-R18). acc: 3 named arrays (no runtime z
// index). grid 384 = 8 xcd x (8m x 6n).
// V epilogue: transposed [bh][dk][kv'], kv' = bits2<->3 swap (split-4 pre-permute).
__global__ __launch_bounds__(256) void gemmqkv_kernel(
    const bf16_t* __restrict__ A,
    const bf16_t* __restrict__ WTq, const bf16_t* __restrict__ WTk, const bf16_t* __restrict__ WTv,
    const float* __restrict__ bq, const float* __restrict__ bk, const float* __restrict__ bv,
    bf16_t* __restrict__ Qo, bf16_t* __restrict__ Ko, bf16_t* __restrict__ Vo) {
    __shared__ __align__(16) bf16_t As[128*64];       // 16 KB
    __shared__ __align__(16) bf16_t Bs[3][128*64];    // 48 KB
    const int tid = threadIdx.x, wave = tid>>6, lane = tid&63;
    const int wm = wave>>1, wn = wave&1;
    const int b = blockIdx.x;
    const int xcd = b & 7, ib = b >> 3;               // 384 = 8 x 48
    const int mtile = xcd*8 + ib/6, ntile = ib % 6;
    const int m0 = mtile*128, n0 = ntile*128;

    f32x4 accQ[4][4], accK[4][4], accV[4][4];
    const f32x4 zf = {0.f,0.f,0.f,0.f};
    #pragma unroll
    for (int m = 0; m < 4; ++m)
        #pragma unroll
        for (int n = 0; n < 4; ++n) { accQ[m][n] = zf; accK[m][n] = zf; accV[m][n] = zf; }

    const int srow = wave*32 + (lane>>3);
    const int scol = (lane&7)*8;
    const bf16_t* Ag  = A   + (size_t)(m0+srow)*DIM + scol;
    const bf16_t* Bgq = WTq + (size_t)(n0+srow)*DIM + scol;
    const bf16_t* Bgk = WTk + (size_t)(n0+srow)*DIM + scol;
    const bf16_t* Bgv = WTv + (size_t)(n0+srow)*DIM + scol;
    const int woff = (wave*32)*64;

    for (int t = 0; t < DIM/64; ++t) {
        const size_t k0 = (size_t)t*64;
        MEMFENCE; __builtin_amdgcn_s_barrier(); MEMFENCE;   // prev-step LDS reads done
        #pragma unroll
        for (int i2 = 0; i2 < 4; ++i2) {
            gload_lds16(Ag  + (size_t)(i2*8)*DIM + k0, &As[woff + i2*8*64]);
            gload_lds16(Bgq + (size_t)(i2*8)*DIM + k0, &Bs[0][woff + i2*8*64]);
            gload_lds16(Bgk + (size_t)(i2*8)*DIM + k0, &Bs[1][woff + i2*8*64]);
            gload_lds16(Bgv + (size_t)(i2*8)*DIM + k0, &Bs[2][woff + i2*8*64]);
        }
        asm volatile("s_waitcnt vmcnt(0)" ::: "memory");
        MEMFENCE; __builtin_amdgcn_s_barrier(); MEMFENCE;   // tiles ready

        #pragma unroll
        for (int ks = 0; ks < 2; ++ks) {
            bf16x8 af[4];
            #pragma unroll
            for (int m = 0; m < 4; ++m)
                af[m] = *(const bf16x8*)&As[(wm*64 + m*16 + (lane&15))*64 + ks*32 + (lane>>4)*8];
            // z = Q
            {
                bf16x8 bfr[4];
                #pragma unroll
                for (int n = 0; n < 4; ++n)
                    bfr[n] = *(const bf16x8*)&Bs[0][(wn*64 + n*16 + (lane&15))*64 + ks*32 + (lane>>4)*8];
                #pragma unroll
                for (int m = 0; m < 4; ++m)
                    #pragma unroll
                    for (int n = 0; n < 4; ++n)
                        accQ[m][n] = __builtin_amdgcn_mfma_f32_16x16x32_bf16(af[m], bfr[n], accQ[m][n], 0, 0, 0);
            }
            // z = K
            {
                bf16x8 bfr[4];
                #pragma unroll
                for (int n = 0; n < 4; ++n)
                    bfr[n] = *(const bf16x8*)&Bs[1][(wn*64 + n*16 + (lane&15))*64 + ks*32 + (lane>>4)*8];
                #pragma unroll
                for (int m = 0; m < 4; ++m)
                    #pragma unroll
                    for (int n = 0; n < 4; ++n)
                        accK[m][n] = __builtin_amdgcn_mfma_f32_16x16x32_bf16(af[m], bfr[n], accK[m][n], 0, 0, 0);
            }
            // z = V
            {
                bf16x8 bfr[4];
                #pragma unroll
                for (int n = 0; n < 4; ++n)
                    bfr[n] = *(const bf16x8*)&Bs[2][(wn*64 + n*16 + (lane&15))*64 + ks*32 + (lane>>4)*8];
                #pragma unroll
                for (int m = 0; m < 4; ++m)
                    #pragma unroll
                    for (int n = 0; n < 4; ++n)
                        accV[m][n] = __builtin_amdgcn_mfma_f32_16x16x32_bf16(af[m], bfr[n], accV[m][n], 0, 0, 0);
            }
        }
    }

    float bvQ[4], bvK[4], bvV[4];
    #pragma unroll
    for (int n = 0; n < 4; ++n) {
        int c = n0 + wn*64 + n*16 + (lane&15);
        bvQ[n] = bq[c]; bvK[n] = bk[c]; bvV[n] = bv[c];
    }

    #pragma unroll
    for (int m = 0; m < 4; ++m) {
        #pragma unroll
        for (int n = 0; n < 4; ++n) {
            #pragma unroll
            for (int r = 0; r < 4; ++r) {
                int R = m0 + wm*64 + m*16 + (lane>>4)*4 + r;
                int C = n0 + wn*64 + n*16 + (lane&15);
                int bi = R>>11, li = R&2047, h = C>>6, d = C&63;
                size_t bh = (size_t)(bi*NHEAD + h);
                // Q (softmax scale folded)
                Qo[(bh*SEQ + li)*DK + d] = (bf16_t)((accQ[m][n][r] + bvQ[n])*SCL);
                // K
                Ko[(bh*SEQ + li)*DK + d] = (bf16_t)(accK[m][n][r] + bvK[n]);
                // V transposed, kv bits2<->3 swapped (split-4 pre-permute)
                int li2 = (li & ~12) | ((li&4)<<1) | ((li&8)>>1);
                Vo[(bh*DK + d)*SEQ + li2] = (bf16_t)(accV[m][n][r] + bvV[n]);
            }
        }
    }
}

// ---------------- GEMM (R13 exact; used for out-proj MODE 1 only) ----------------
template<int MODE>
__global__ __launch_bounds__(256) void gemm_kernel(
    const bf16_t* __restrict__ A,
    const bf16_t* __restrict__ WTa, const bf16_t* __restrict__ WTb, const bf16_t* __restrict__ WTc,
    const float* __restrict__ ba, const float* __restrict__ bb, const float* __restrict__ bc,
    bf16_t* __restrict__ Qo, bf16_t* __restrict__ Ko, bf16_t* __restrict__ Vo,
    float* __restrict__ Oo) {
    __shared__ __align__(16) bf16_t As[2][128*64];
    __shared__ __align__(16) bf16_t Bs[2][128*64];
    const int tid = threadIdx.x, wave = tid>>6, lane = tid&63;
    const int wm = wave>>1, wn = wave&1;
    const int b = blockIdx.x;
    const int xcd = b & 7, ib = b >> 3;
    int z, ntile, mtile;
    if (MODE == 0) { z = ib % 3; ntile = (ib/3) % 6; mtile = xcd*8 + ib/18; }
    else           { z = 0;      ntile = ib % 6;     mtile = xcd*8 + ib/6;  }
    const int m0 = mtile*128, n0 = ntile*128;
    const bf16_t* WT  = (z==0) ? WTa : (z==1 ? WTb : WTc);
    const float* bias = (z==0) ? ba  : (z==1 ? bb  : bc);

    f32x4 acc[4][4];
    const f32x4 zf = {0.f,0.f,0.f,0.f};
    #pragma unroll
    for (int m = 0; m < 4; ++m)
        #pragma unroll
        for (int n = 0; n < 4; ++n) acc[m][n] = zf;

    const int srow = wave*32 + (lane>>3);
    const int scol = (lane&7)*8;
    const bf16_t* Ag = A  + (size_t)(m0+srow)*DIM + scol;
    const bf16_t* Bg = WT + (size_t)(n0+srow)*DIM + scol;
    const int woff = (wave*32)*64;

    #pragma unroll
    for (int i2 = 0; i2 < 4; ++i2) {
        gload_lds16(Ag + (size_t)(i2*8)*DIM, &As[0][woff + i2*8*64]);
        gload_lds16(Bg + (size_t)(i2*8)*DIM, &Bs[0][woff + i2*8*64]);
    }

    int cur = 0;
    for (int t = 0; t < DIM/64; ++t) {
        if (t < DIM/64 - 1) {
            const size_t k1 = (size_t)(t+1)*64;
            #pragma unroll
            for (int i2 = 0; i2 < 4; ++i2) {
                gload_lds16(Ag + (size_t)(i2*8)*DIM + k1, &As[cur^1][woff + i2*8*64]);
                gload_lds16(Bg + (size_t)(i2*8)*DIM + k1, &Bs[cur^1][woff + i2*8*64]);
            }
            asm volatile("s_waitcnt vmcnt(8)" ::: "memory");
        } else {
            asm volatile("s_waitcnt vmcnt(0)" ::: "memory");
        }
        MEMFENCE; __builtin_amdgcn_s_barrier(); MEMFENCE;

        #pragma unroll
        for (int ks = 0; ks < 2; ++ks) {
            bf16x8 af[4], bfr[4];
            #pragma unroll
            for (int m = 0; m < 4; ++m)
                af[m]  = *(const bf16x8*)&As[cur][(wm*64 + m*16 + (lane&15))*64 + ks*32 + (lane>>4)*8];
            #pragma unroll
            for (int n = 0; n < 4; ++n)
                bfr[n] = *(const bf16x8*)&Bs[cur][(wn*64 + n*16 + (lane&15))*64 + ks*32 + (lane>>4)*8];
            #pragma unroll
            for (int m = 0; m < 4; ++m)
                #pragma unroll
                for (int n = 0; n < 4; ++n)
                    acc[m][n] = __builtin_amdgcn_mfma_f32_16x16x32_bf16(af[m], bfr[n], acc[m][n], 0, 0, 0);
        }
        MEMFENCE; __builtin_amdgcn_s_barrier(); MEMFENCE;
        cur ^= 1;
    }

    float bvv[4];
    #pragma unroll
    for (int n = 0; n < 4; ++n) bvv[n] = bias[n0 + wn*64 + n*16 + (lane&15)];

    #pragma unroll
    for (int m = 0; m < 4; ++m) {
        #pragma unroll
        for (int n = 0; n < 4; ++n) {
            #pragma unroll
            for (int r = 0; r < 4; ++r) {
                float val = acc[m][n][r] + bvv[n];
                int R = m0 + wm*64 + m*16 + (lane>>4)*4 + r;
                int C = n0 + wn*64 + n*16 + (lane&15);
                if (MODE == 1) {
                    Oo[(size_t)R*DIM + C] = val;
                } else {
                    int bi = R>>11, li = R&2047, h = C>>6, d = C&63;
                    size_t bh = (size_t)(bi*NHEAD + h);
                    if      (z==0) Qo[(bh*SEQ + li)*DK + d] = (bf16_t)(val*SCL);
                    else if (z==1) Ko[(bh*SEQ + li)*DK + d] = (bf16_t)val;
                    else {
                        int li2 = (li & ~12) | ((li&4)<<1) | ((li&8)>>1);
                        Vo[(bh*DK + d)*SEQ + li2] = (bf16_t)val;
                    }
                }
            }
        }
    }
}

// ---------------- flash attention: 32x32 swapped MFMA, zero-shuffle P, FIXED-MAX ----------------
// (R12/R13/R20 exact: 4-wave blocks, Q-tile 128, grid 768, XCD-clustered)
#define NT (SEQ/64)

__global__ __launch_bounds__(256) void attn_kernel(
    const bf16_t* __restrict__ Q, const bf16_t* __restrict__ K, const bf16_t* __restrict__ VT,
    const int* __restrict__ mask, bf16_t* __restrict__ X) {
    __shared__ __align__(16) bf16_t lds[2*8192];      // [buf][ K 64x64 | VT 64x64 ]
    const int tid = threadIdx.x, wv = tid>>6, lane = tid&63;
    const int lo5 = lane&31, hi5 = lane>>5;
    const int b = blockIdx.x;
    const int xcd = b & 7, ii = b >> 3;
    const int bh = xcd*6 + (ii>>4), qt = ii & 15;
    const int bi = bh/NHEAD, h = bh%NHEAD;
    const bf16_t* Qb = Q  + (size_t)bh*SEQ*DK;
    const bf16_t* Kb = K  + (size_t)bh*SEQ*DK;
    const bf16_t* Vb = VT + (size_t)bh*DK*SEQ;
    const int* mk = mask + (size_t)bi*SEQ + lo5;
    const int q0 = qt*128 + wv*32;

    int mOk = 1;
    {
        const int4* m4 = (const int4*)(mask + (size_t)bi*SEQ);
        #pragma unroll
        for (int i2 = 0; i2 < 8; ++i2) {
            int4 v = m4[lane + i2*64];
            mOk &= (v.x != 0) & (v.y != 0) & (v.z != 0) & (v.w != 0);
        }
    }
    const int mAll = __all(mOk);

    bf16x8 qf[4];
    #pragma unroll
    for (int ks = 0; ks < 4; ++ks)
        qf[ks] = *(const bf16x8*)&Qb[(size_t)(q0 + lo5)*DK + ks*16 + hi5*8];

    f32x16 O0, O1;
    #pragma unroll
    for (int r = 0; r < 16; ++r) { O0[r] = 0.f; O1[r] = 0.f; }
    float lsum = 0.f;

    bf16x8 onesb = {};
    if (hi5 == 0) onesb[0] = (bf16_t)1.0f;

    const int srow  = wv*16 + (lane>>3);
    const int sslot = (lane&7) ^ (srow&7);
    const bf16_t* Kg = Kb + (size_t)srow*DK  + sslot*8;
    const bf16_t* Vg = Vb + (size_t)srow*SEQ + sslot*8;
    int koff[4];
    #pragma unroll
    for (int ks = 0; ks < 4; ++ks) koff[ks] = (((2*ks + hi5) ^ (lo5 & 7)) << 3);

    #pragma unroll
    for (int i = 0; i < 2; ++i) {
        gload_lds16(Kg + (size_t)(i*8)*DK,  lds +        (wv*16 + i*8)*64);
        gload_lds16(Vg + (size_t)(i*8)*SEQ, lds + 4096 + (wv*16 + i*8)*64);
    }

    int cur = 0;
    for (int t = 0; t < NT; ++t) {
        const int kv0 = t*64;
        if (t < NT-1) {
            bf16_t* nb = lds + (cur^1)*8192;
            #pragma unroll
            for (int i = 0; i < 2; ++i) {
                gload_lds16(Kg + (size_t)(kv0+64)*DK + (size_t)(i*8)*DK,  nb +        (wv*16 + i*8)*64);
                gload_lds16(Vg + (kv0+64)            + (size_t)(i*8)*SEQ, nb + 4096 + (wv*16 + i*8)*64);
            }
            asm volatile("s_waitcnt vmcnt(4)" ::: "memory");
        } else {
            asm volatile("s_waitcnt vmcnt(0)" ::: "memory");
        }
        MEMFENCE; __builtin_amdgcn_s_barrier(); MEMFENCE;

        const bf16_t* Kt = lds + cur*8192;
        const bf16_t* Vt = lds + cur*8192 + 4096;

        f32x16 s0, s1;
        #pragma unroll
        for (int r = 0; r < 16; ++r) { s0[r] = -12.f; s1[r] = -12.f; }
        #pragma unroll
        for (int ks = 0; ks < 4; ++ks) {
            bf16x8 a0 = *(const bf16x8*)&Kt[ lo5     *64 + koff[ks]];
            bf16x8 a1 = *(const bf16x8*)&Kt[(32+lo5)*64 + koff[ks]];
            s0 = __builtin_amdgcn_mfma_f32_32x32x16_bf16(a0, qf[ks], s0, 0, 0, 0);
            s1 = __builtin_amdgcn_mfma_f32_32x32x16_bf16(a1, qf[ks], s1, 0, 0, 0);
        }
        if (!mAll) {
            int mv0 = mk[kv0], mv1 = mk[kv0 + 32];
            bf16x8 ba = {};
            ba[0] = mv0 ? (bf16_t)0.f : (bf16_t)(-1024.0f);
            s0 = __builtin_amdgcn_mfma_f32_32x32x16_bf16(ba, onesb, s0, 0, 0, 0);
            ba[0] = mv1 ? (bf16_t)0.f : (bf16_t)(-1024.0f);
            s1 = __builtin_amdgcn_mfma_f32_32x32x16_bf16(ba, onesb, s1, 0, 0, 0);
        }

        #pragma unroll
        for (int r = 0; r < 16; ++r) {
            s0[r] = __builtin_amdgcn_exp2f(s0[r]);
            s1[r] = __builtin_amdgcn_exp2f(s1[r]);
        }
        float t01[16];
        #pragma unroll
        for (int r = 0; r < 16; ++r) t01[r] = s0[r] + s1[r];
        float u[8];
        #pragma unroll
        for (int r = 0; r < 8; ++r) u[r] = t01[r] + t01[r+8];
        float w0 = (u[0]+u[1]) + (u[2]+u[3]);
        float w1 = (u[4]+u[5]) + (u[6]+u[7]);
        float ps = w0 + w1;
        lsum += ps + __shfl_xor(ps, 32);

        bf16x8 pf0, pf1, pf2, pf3;
        #pragma unroll
        for (int j = 0; j < 8; ++j) {
            pf0[j] = (bf16_t)s0[j];
            pf1[j] = (bf16_t)s0[8+j];
            pf2[j] = (bf16_t)s1[j];
            pf3[j] = (bf16_t)s1[8+j];
        }

        #pragma unroll
        for (int ks = 0; ks < 4; ++ks) {
            bf16x8 pb = (ks==0) ? pf0 : (ks==1) ? pf1 : (ks==2) ? pf2 : pf3;
            bf16x8 a0 = *(const bf16x8*)&Vt[ lo5     *64 + koff[ks]];
            bf16x8 a1 = *(const bf16x8*)&Vt[(32+lo5)*64 + koff[ks]];
            O0 = __builtin_amdgcn_mfma_f32_32x32x16_bf16(a0, pb, O0, 0, 0, 0);
            O1 = __builtin_amdgcn_mfma_f32_32x32x16_bf16(a1, pb, O1, 0, 0, 0);
        }
        MEMFENCE; __builtin_amdgcn_s_barrier(); MEMFENCE;
        cur ^= 1;
    }

    float rl = __builtin_amdgcn_rcpf(lsum);
    const size_t rowb = (size_t)(bi*SEQ + q0 + lo5)*DIM + h*DK;
    #pragma unroll
    for (int g = 0; g < 4; ++g) {
        bf16x4 v0, v1;
        #pragma unroll
        for (int j = 0; j < 4; ++j) {
            v0[j] = (bf16_t)(O0[g*4+j] * rl);
            v1[j] = (bf16_t)(O1[g*4+j] * rl);
        }
        *(bf16x4*)&X[rowb + g*8 + hi5*4]      = v0;
        *(bf16x4*)&X[rowb + 32 + g*8 + hi5*4] = v1;
    }
}

extern "C" void kernel_launch(void* const* d_in, const int* in_sizes, int n_in,
                              void* d_out, int out_size, void* d_ws, size_t ws_size,
                              hipStream_t stream) {
    (void)in_sizes; (void)n_in; (void)out_size; (void)ws_size;
    const float* qkv = (const float*)d_in[0];
    const int*  mask = (const int*)d_in[1];
    const float* Wq = (const float*)d_in[2];
    const float* bq = (const float*)d_in[3];
    const float* Wk = (const float*)d_in[4];
    const float* bk = (const float*)d_in[5];
    const float* Wv = (const float*)d_in[6];
    const float* bv = (const float*)d_in[7];
    const float* Wo = (const float*)d_in[8];
    const float* bo = (const float*)d_in[9];
    float* out = (float*)d_out;

    char* ws = (char*)d_ws;
    size_t off = 0;
    auto carve = [&](size_t bytes) { void* p = ws + off; off += (bytes + 255) & ~(size_t)255; return p; };
    const size_t actN = (size_t)ROWS*DIM;
    bf16_t* Abf = (bf16_t*)carve(actN*2);
    bf16_t* WTq = (bf16_t*)carve((size_t)DIM*DIM*2);
    bf16_t* WTk = (bf16_t*)carve((size_t)DIM*DIM*2);
    bf16_t* WTv = (bf16_t*)carve((size_t)DIM*DIM*2);
    bf16_t* WTo = (bf16_t*)carve((size_t)DIM*DIM*2);
    bf16_t* Qb  = (bf16_t*)carve(actN*2);
    bf16_t* Kb  = (bf16_t*)carve(actN*2);
    bf16_t* VTb = (bf16_t*)carve(actN*2);
    bf16_t* Xb  = (bf16_t*)carve(actN*2);

    cast_bf16_kernel<<<dim3(ROWS*DIM/8/256), dim3(256), 0, stream>>>(qkv, Abf);
    wtrans_kernel<<<dim3(24,24,4), dim3(32,8), 0, stream>>>(Wq, Wk, Wv, Wo, WTq, WTk, WTv, WTo);
    gemmqkv_kernel<<<dim3(384), dim3(256), 0, stream>>>(Abf, WTq, WTk, WTv, bq, bk, bv,
                                                        Qb, Kb, VTb);
    attn_kernel<<<dim3(768), dim3(256), 0, stream>>>(Qb, Kb, VTb, mask, Xb);
    gemm_kernel<1><<<dim3(384), dim3(256), 0, stream>>>(Xb, WTo, WTo, WTo, bo, bo, bo,
                                                        nullptr, nullptr, nullptr, out);
}

// Round 22
// 168.661 us; speedup vs baseline: 1.0246x; 1.0246x over previous
//
#include <hip/hip_runtime.h>
#include <hip/hip_bf16.h>
#include <stdint.h>

#define DIM  768
#define NHEAD 12
#define DK   64
#define BATCH 4
#define SEQ  2048
#define ROWS (BATCH*SEQ)   // 8192
#define SCL  0.1803368801111204f   /* (1/sqrt(64)) * log2(e) — folded into Q gemm epilogue */

typedef __bf16 bf16_t;
typedef bf16_t bf16x8 __attribute__((ext_vector_type(8)));
typedef bf16_t bf16x4 __attribute__((ext_vector_type(4)));
typedef float  f32x4  __attribute__((ext_vector_type(4)));
typedef float  f32x16 __attribute__((ext_vector_type(16)));

typedef unsigned int __attribute__((address_space(1)))* as1p;
typedef unsigned int __attribute__((address_space(3)))* as3p;

__device__ __forceinline__ void gload_lds16(const void* g, void* l) {
    __builtin_amdgcn_global_load_lds((as1p)g, (as3p)l, 16, 0, 0);
}
#define MEMFENCE asm volatile("" ::: "memory")
// NOTE: inline-asm v_permlane32_swap_b32 is BANNED (convicted R3/R4/R5/R7).

// ---------------- cast qkv fp32 -> bf16 ----------------
__global__ void cast_bf16_kernel(const float* __restrict__ in, bf16_t* __restrict__ out) {
    int i = blockIdx.x * 256 + threadIdx.x;
    const float4* p = (const float4*)in;
    float4 a = p[(size_t)i*2], b = p[(size_t)i*2+1];
    bf16x8 v;
    v[0]=(bf16_t)a.x; v[1]=(bf16_t)a.y; v[2]=(bf16_t)a.z; v[3]=(bf16_t)a.w;
    v[4]=(bf16_t)b.x; v[5]=(bf16_t)b.y; v[6]=(bf16_t)b.z; v[7]=(bf16_t)b.w;
    *(bf16x8*)(out + (size_t)i*8) = v;
}

// ---------------- transpose+cast weights: WT[j][i] = W[i][j] ----------------
__global__ void wtrans_kernel(const float* __restrict__ W0, const float* __restrict__ W1,
                              const float* __restrict__ W2, const float* __restrict__ W3,
                              bf16_t* __restrict__ T0, bf16_t* __restrict__ T1,
                              bf16_t* __restrict__ T2, bf16_t* __restrict__ T3) {
    const float* W = blockIdx.z==0?W0 : blockIdx.z==1?W1 : blockIdx.z==2?W2 : W3;
    bf16_t*      T = blockIdx.z==0?T0 : blockIdx.z==1?T1 : blockIdx.z==2?T2 : T3;
    __shared__ float tile[32][33];
    int tx = threadIdx.x, ty = threadIdx.y;          // 32 x 8
    int c = blockIdx.x*32 + tx;
    #pragma unroll
    for (int r = 0; r < 32; r += 8)
        tile[ty+r][tx] = W[(size_t)(blockIdx.y*32 + ty + r)*DIM + c];
    __syncthreads();
    int oc = blockIdx.y*32 + tx;
    #pragma unroll
    for (int r = 0; r < 32; r += 8)
        T[(size_t)(blockIdx.x*32 + ty + r)*DIM + oc] = (bf16_t)tile[tx][ty+r];
}

// ---------------- GEMM (R13 exact: dbuf BK=64, counted vmcnt(8), raw barriers) ----------------
// Best-measured GEMM config of the session. 1D grid, XCD-clustered:
// MODE 0: 1152 = 8 xcd x (8m x 6n x 3z); MODE 1: 384.
// z==2 (V): written transposed [bh][dk][kv'], kv' = bits2<->3 swap (split-4).
template<int MODE>
__global__ __launch_bounds__(256) void gemm_kernel(
    const bf16_t* __restrict__ A,
    const bf16_t* __restrict__ WTa, const bf16_t* __restrict__ WTb, const bf16_t* __restrict__ WTc,
    const float* __restrict__ ba, const float* __restrict__ bb, const float* __restrict__ bc,
    bf16_t* __restrict__ Qo, bf16_t* __restrict__ Ko, bf16_t* __restrict__ Vo,
    float* __restrict__ Oo) {
    __shared__ __align__(16) bf16_t As[2][128*64];
    __shared__ __align__(16) bf16_t Bs[2][128*64];
    const int tid = threadIdx.x, wave = tid>>6, lane = tid&63;
    const int wm = wave>>1, wn = wave&1;
    const int b = blockIdx.x;
    const int xcd = b & 7, ib = b >> 3;
    int z, ntile, mtile;
    if (MODE == 0) { z = ib % 3; ntile = (ib/3) % 6; mtile = xcd*8 + ib/18; }
    else           { z = 0;      ntile = ib % 6;     mtile = xcd*8 + ib/6;  }
    const int m0 = mtile*128, n0 = ntile*128;
    const bf16_t* WT  = (z==0) ? WTa : (z==1 ? WTb : WTc);
    const float* bias = (z==0) ? ba  : (z==1 ? bb  : bc);

    f32x4 acc[4][4];
    const f32x4 zf = {0.f,0.f,0.f,0.f};
    #pragma unroll
    for (int m = 0; m < 4; ++m)
        #pragma unroll
        for (int n = 0; n < 4; ++n) acc[m][n] = zf;

    const int srow = wave*32 + (lane>>3);
    const int scol = (lane&7)*8;
    const bf16_t* Ag = A  + (size_t)(m0+srow)*DIM + scol;
    const bf16_t* Bg = WT + (size_t)(n0+srow)*DIM + scol;
    const int woff = (wave*32)*64;

    #pragma unroll
    for (int i2 = 0; i2 < 4; ++i2) {
        gload_lds16(Ag + (size_t)(i2*8)*DIM, &As[0][woff + i2*8*64]);
        gload_lds16(Bg + (size_t)(i2*8)*DIM, &Bs[0][woff + i2*8*64]);
    }

    int cur = 0;
    for (int t = 0; t < DIM/64; ++t) {
        if (t < DIM/64 - 1) {
            const size_t k1 = (size_t)(t+1)*64;
            #pragma unroll
            for (int i2 = 0; i2 < 4; ++i2) {
                gload_lds16(Ag + (size_t)(i2*8)*DIM + k1, &As[cur^1][woff + i2*8*64]);
                gload_lds16(Bg + (size_t)(i2*8)*DIM + k1, &Bs[cur^1][woff + i2*8*64]);
            }
            asm volatile("s_waitcnt vmcnt(8)" ::: "memory");
        } else {
            asm volatile("s_waitcnt vmcnt(0)" ::: "memory");
        }
        MEMFENCE; __builtin_amdgcn_s_barrier(); MEMFENCE;

        #pragma unroll
        for (int ks = 0; ks < 2; ++ks) {
            bf16x8 af[4], bfr[4];
            #pragma unroll
            for (int m = 0; m < 4; ++m)
                af[m]  = *(const bf16x8*)&As[cur][(wm*64 + m*16 + (lane&15))*64 + ks*32 + (lane>>4)*8];
            #pragma unroll
            for (int n = 0; n < 4; ++n)
                bfr[n] = *(const bf16x8*)&Bs[cur][(wn*64 + n*16 + (lane&15))*64 + ks*32 + (lane>>4)*8];
            #pragma unroll
            for (int m = 0; m < 4; ++m)
                #pragma unroll
                for (int n = 0; n < 4; ++n)
                    acc[m][n] = __builtin_amdgcn_mfma_f32_16x16x32_bf16(af[m], bfr[n], acc[m][n], 0, 0, 0);
        }
        MEMFENCE; __builtin_amdgcn_s_barrier(); MEMFENCE;
        cur ^= 1;
    }

    float bvv[4];
    #pragma unroll
    for (int n = 0; n < 4; ++n) bvv[n] = bias[n0 + wn*64 + n*16 + (lane&15)];

    #pragma unroll
    for (int m = 0; m < 4; ++m) {
        #pragma unroll
        for (int n = 0; n < 4; ++n) {
            #pragma unroll
            for (int r = 0; r < 4; ++r) {
                float val = acc[m][n][r] + bvv[n];
                int R = m0 + wm*64 + m*16 + (lane>>4)*4 + r;
                int C = n0 + wn*64 + n*16 + (lane&15);
                if (MODE == 1) {
                    Oo[(size_t)R*DIM + C] = val;
                } else {
                    int bi = R>>11, li = R&2047, h = C>>6, d = C&63;
                    size_t bh = (size_t)(bi*NHEAD + h);
                    if      (z==0) Qo[(bh*SEQ + li)*DK + d] = (bf16_t)(val*SCL);
                    else if (z==1) Ko[(bh*SEQ + li)*DK + d] = (bf16_t)val;
                    else {
                        // V^T with kv bits2<->3 swapped (split-4 pre-permute)
                        int li2 = (li & ~12) | ((li&4)<<1) | ((li&8)>>1);
                        Vo[(bh*DK + d)*SEQ + li2] = (bf16_t)val;
                    }
                }
            }
        }
    }
}

// ---------------- flash attention: 32x32 swapped MFMA, zero-shuffle P, FIXED-MAX ----------------
// (R12/R13/R20 exact: 4-wave blocks, Q-tile 128, grid 768, XCD-clustered)
#define NT (SEQ/64)

__global__ __launch_bounds__(256) void attn_kernel(
    const bf16_t* __restrict__ Q, const bf16_t* __restrict__ K, const bf16_t* __restrict__ VT,
    const int* __restrict__ mask, bf16_t* __restrict__ X) {
    __shared__ __align__(16) bf16_t lds[2*8192];      // [buf][ K 64x64 | VT 64x64 ]
    const int tid = threadIdx.x, wv = tid>>6, lane = tid&63;
    const int lo5 = lane&31, hi5 = lane>>5;
    const int b = blockIdx.x;
    const int xcd = b & 7, ii = b >> 3;
    const int bh = xcd*6 + (ii>>4), qt = ii & 15;
    const int bi = bh/NHEAD, h = bh%NHEAD;
    const bf16_t* Qb = Q  + (size_t)bh*SEQ*DK;
    const bf16_t* Kb = K  + (size_t)bh*SEQ*DK;
    const bf16_t* Vb = VT + (size_t)bh*DK*SEQ;
    const int* mk = mask + (size_t)bi*SEQ + lo5;
    const int q0 = qt*128 + wv*32;

    int mOk = 1;
    {
        const int4* m4 = (const int4*)(mask + (size_t)bi*SEQ);
        #pragma unroll
        for (int i2 = 0; i2 < 8; ++i2) {
            int4 v = m4[lane + i2*64];
            mOk &= (v.x != 0) & (v.y != 0) & (v.z != 0) & (v.w != 0);
        }
    }
    const int mAll = __all(mOk);

    bf16x8 qf[4];
    #pragma unroll
    for (int ks = 0; ks < 4; ++ks)
        qf[ks] = *(const bf16x8*)&Qb[(size_t)(q0 + lo5)*DK + ks*16 + hi5*8];

    f32x16 O0, O1;
    #pragma unroll
    for (int r = 0; r < 16; ++r) { O0[r] = 0.f; O1[r] = 0.f; }
    float lsum = 0.f;

    bf16x8 onesb = {};
    if (hi5 == 0) onesb[0] = (bf16_t)1.0f;

    const int srow  = wv*16 + (lane>>3);
    const int sslot = (lane&7) ^ (srow&7);
    const bf16_t* Kg = Kb + (size_t)srow*DK  + sslot*8;
    const bf16_t* Vg = Vb + (size_t)srow*SEQ + sslot*8;
    int koff[4];
    #pragma unroll
    for (int ks = 0; ks < 4; ++ks) koff[ks] = (((2*ks + hi5) ^ (lo5 & 7)) << 3);

    #pragma unroll
    for (int i = 0; i < 2; ++i) {
        gload_lds16(Kg + (size_t)(i*8)*DK,  lds +        (wv*16 + i*8)*64);
        gload_lds16(Vg + (size_t)(i*8)*SEQ, lds + 4096 + (wv*16 + i*8)*64);
    }

    int cur = 0;
    for (int t = 0; t < NT; ++t) {
        const int kv0 = t*64;
        if (t < NT-1) {
            bf16_t* nb = lds + (cur^1)*8192;
            #pragma unroll
            for (int i = 0; i < 2; ++i) {
                gload_lds16(Kg + (size_t)(kv0+64)*DK + (size_t)(i*8)*DK,  nb +        (wv*16 + i*8)*64);
                gload_lds16(Vg + (kv0+64)            + (size_t)(i*8)*SEQ, nb + 4096 + (wv*16 + i*8)*64);
            }
            asm volatile("s_waitcnt vmcnt(4)" ::: "memory");
        } else {
            asm volatile("s_waitcnt vmcnt(0)" ::: "memory");
        }
        MEMFENCE; __builtin_amdgcn_s_barrier(); MEMFENCE;

        const bf16_t* Kt = lds + cur*8192;
        const bf16_t* Vt = lds + cur*8192 + 4096;

        f32x16 s0, s1;
        #pragma unroll
        for (int r = 0; r < 16; ++r) { s0[r] = -12.f; s1[r] = -12.f; }
        #pragma unroll
        for (int ks = 0; ks < 4; ++ks) {
            bf16x8 a0 = *(const bf16x8*)&Kt[ lo5     *64 + koff[ks]];
            bf16x8 a1 = *(const bf16x8*)&Kt[(32+lo5)*64 + koff[ks]];
            s0 = __builtin_amdgcn_mfma_f32_32x32x16_bf16(a0, qf[ks], s0, 0, 0, 0);
            s1 = __builtin_amdgcn_mfma_f32_32x32x16_bf16(a1, qf[ks], s1, 0, 0, 0);
        }
        if (!mAll) {
            int mv0 = mk[kv0], mv1 = mk[kv0 + 32];
            bf16x8 ba = {};
            ba[0] = mv0 ? (bf16_t)0.f : (bf16_t)(-1024.0f);
            s0 = __builtin_amdgcn_mfma_f32_32x32x16_bf16(ba, onesb, s0, 0, 0, 0);
            ba[0] = mv1 ? (bf16_t)0.f : (bf16_t)(-1024.0f);
            s1 = __builtin_amdgcn_mfma_f32_32x32x16_bf16(ba, onesb, s1, 0, 0, 0);
        }

        #pragma unroll
        for (int r = 0; r < 16; ++r) {
            s0[r] = __builtin_amdgcn_exp2f(s0[r]);
            s1[r] = __builtin_amdgcn_exp2f(s1[r]);
        }
        float t01[16];
        #pragma unroll
        for (int r = 0; r < 16; ++r) t01[r] = s0[r] + s1[r];
        float u[8];
        #pragma unroll
        for (int r = 0; r < 8; ++r) u[r] = t01[r] + t01[r+8];
        float w0 = (u[0]+u[1]) + (u[2]+u[3]);
        float w1 = (u[4]+u[5]) + (u[6]+u[7]);
        float ps = w0 + w1;
        lsum += ps + __shfl_xor(ps, 32);

        bf16x8 pf0, pf1, pf2, pf3;
        #pragma unroll
        for (int j = 0; j < 8; ++j) {
            pf0[j] = (bf16_t)s0[j];
            pf1[j] = (bf16_t)s0[8+j];
            pf2[j] = (bf16_t)s1[j];
            pf3[j] = (bf16_t)s1[8+j];
        }

        #pragma unroll
        for (int ks = 0; ks < 4; ++ks) {
            bf16x8 pb = (ks==0) ? pf0 : (ks==1) ? pf1 : (ks==2) ? pf2 : pf3;
            bf16x8 a0 = *(const bf16x8*)&Vt[ lo5     *64 + koff[ks]];
            bf16x8 a1 = *(const bf16x8*)&Vt[(32+lo5)*64 + koff[ks]];
            O0 = __builtin_amdgcn_mfma_f32_32x32x16_bf16(a0, pb, O0, 0, 0, 0);
            O1 = __builtin_amdgcn_mfma_f32_32x32x16_bf16(a1, pb, O1, 0, 0, 0);
        }
        MEMFENCE; __builtin_amdgcn_s_barrier(); MEMFENCE;
        cur ^= 1;
    }

    float rl = __builtin_amdgcn_rcpf(lsum);
    const size_t rowb = (size_t)(bi*SEQ + q0 + lo5)*DIM + h*DK;
    #pragma unroll
    for (int g = 0; g < 4; ++g) {
        bf16x4 v0, v1;
        #pragma unroll
        for (int j = 0; j < 4; ++j) {
            v0[j] = (bf16_t)(O0[g*4+j] * rl);
            v1[j] = (bf16_t)(O1[g*4+j] * rl);
        }
        *(bf16x4*)&X[rowb + g*8 + hi5*4]      = v0;
        *(bf16x4*)&X[rowb + 32 + g*8 + hi5*4] = v1;
    }
}

extern "C" void kernel_launch(void* const* d_in, const int* in_sizes, int n_in,
                              void* d_out, int out_size, void* d_ws, size_t ws_size,
                              hipStream_t stream) {
    (void)in_sizes; (void)n_in; (void)out_size; (void)ws_size;
    const float* qkv = (const float*)d_in[0];
    const int*  mask = (const int*)d_in[1];
    const float* Wq = (const float*)d_in[2];
    const float* bq = (const float*)d_in[3];
    const float* Wk = (const float*)d_in[4];
    const float* bk = (const float*)d_in[5];
    const float* Wv = (const float*)d_in[6];
    const float* bv = (const float*)d_in[7];
    const float* Wo = (const float*)d_in[8];
    const float* bo = (const float*)d_in[9];
    float* out = (float*)d_out;

    char* ws = (char*)d_ws;
    size_t off = 0;
    auto carve = [&](size_t bytes) { void* p = ws + off; off += (bytes + 255) & ~(size_t)255; return p; };
    const size_t actN = (size_t)ROWS*DIM;
    bf16_t* Abf = (bf16_t*)carve(actN*2);
    bf16_t* WTq = (bf16_t*)carve((size_t)DIM*DIM*2);
    bf16_t* WTk = (bf16_t*)carve((size_t)DIM*DIM*2);
    bf16_t* WTv = (bf16_t*)carve((size_t)DIM*DIM*2);
    bf16_t* WTo = (bf16_t*)carve((size_t)DIM*DIM*2);
    bf16_t* Qb  = (bf16_t*)carve(actN*2);
    bf16_t* Kb  = (bf16_t*)carve(actN*2);
    bf16_t* VTb = (bf16_t*)carve(actN*2);
    bf16_t* Xb  = (bf16_t*)carve(actN*2);

    cast_bf16_kernel<<<dim3(ROWS*DIM/8/256), dim3(256), 0, stream>>>(qkv, Abf);
    wtrans_kernel<<<dim3(24,24,4), dim3(32,8), 0, stream>>>(Wq, Wk, Wv, Wo, WTq, WTk, WTv, WTo);
    gemm_kernel<0><<<dim3(1152), dim3(256), 0, stream>>>(Abf, WTq, WTk, WTv, bq, bk, bv,
                                                         Qb, Kb, VTb, nullptr);
    attn_kernel<<<dim3(768), dim3(256), 0, stream>>>(Qb, Kb, VTb, mask, Xb);
    gemm_kernel<1><<<dim3(384), dim3(256), 0, stream>>>(Xb, WTo, WTo, WTo, bo, bo, bo,
                                                        nullptr, nullptr, nullptr, out);
}